// Round 25
// baseline (1911.296 us; speedup 1.0000x reference)
//
#include <hip/hip_runtime.h>
#include <stdint.h>

#pragma clang fp contract(off)

constexpr int B_ = 1024, IN_ = 2048, H0_ = 1024, H1_ = 1024, OUT_ = 512;
constexpr int TC = 4;        // timesteps per chunk
constexpr int NCHUNK = 4;    // 16 / TC
constexpr int PQ = 512;      // K-panel width (bitwise-verified in round 16)

// Arithmetic fence: forces the f32 value to materialize — kills FMA contraction
// and reassociation across this point even under -ffp-contract=fast.
static __device__ __forceinline__ float fencef(float x) {
  asm volatile("" : "+v"(x));
  return x;
}

// ---------- transpose chunk: X[b][i][t0..t0+3] -> Xt[tt*B + b][i] (f32) ----------
__global__ void transpose_x4(const float* __restrict__ X, float* __restrict__ Xt, int t0) {
  int idx = blockIdx.x * 256 + threadIdx.x;  // b*IN + i
  int b = idx >> 11, i = idx & (IN_ - 1);
  float4 v = *(const float4*)(X + (size_t)idx * 16 + t0);  // 4 consecutive t's
  Xt[(size_t)b * IN_ + i] = v.x;
  Xt[(size_t)(B_ + b) * IN_ + i] = v.y;
  Xt[(size_t)(2 * B_ + b) * IN_ + i] = v.z;
  Xt[(size_t)(3 * B_ + b) * IN_ + i] = v.w;
}

// ---------- f32 NT GEMM, ONE 512-panel per block, 8x8 micro @ 256 thr ----------
// Panel p of C[M][N]: acc = sum_{k=512p..512p+511} fma(A[m,k], B[n,k], acc),
// single accumulator, ascending k, f32 FMA — bitwise-identical chain to the
// round-16..24 passing kernels. r24's model: LDS-pipe-bound at 1.125 cy/FMA
// (3 b128 reads / 32 FMA). This shape reads 4 b128 / 64 FMA (0.84 cy/FMA incl
// writes) at 4 waves/SIMD: BM=128, BN=128, BK=16, 256 thr, 8x8 micro, dbuf,
// one barrier per K-tile.
__global__ __launch_bounds__(256) void gemm_panel(
    const float* __restrict__ A, const float* __restrict__ Bw,
    float* __restrict__ ZP, size_t pstride, int Ntiles, int K, int N) {
  __shared__ float As[2][16][132];  // k-major, padded
  __shared__ float Bs[2][16][132];

  // bijective XCD swizzle (all grids here are multiples of 8)
  int bid = blockIdx.x, cpx = gridDim.x >> 3;
  int wg = (bid & 7) * cpx + (bid >> 3);
  int tpp = (gridDim.x / ((K + PQ - 1) / PQ));     // tiles per panel = Mt*Nt
  int p = wg / tpp, r = wg - p * tpp;
  int bm = r / Ntiles, bn = r - bm * Ntiles;

  int tid = threadIdx.x;
  int ra = tid >> 1, ca = (tid & 1) * 8;   // staging: row 0..127, 8-k half
  int tx = tid & 15, ty = tid >> 4;        // micro-tile: cols tx*8.., rows ty*8..

  float acc[8][8] = {};   // THE panel chain accumulators (init 0, ascending k)
  const size_t rowA = (size_t)(bm * 128 + ra) * K + p * PQ;
  const size_t rowB = (size_t)(bn * 128 + ra) * K + p * PQ;

  float4 a0, a1, b0, b1;  // staging registers

#define LOADT(kk)                                           \
  do {                                                      \
    a0 = *(const float4*)(A + rowA + (kk) + ca);            \
    a1 = *(const float4*)(A + rowA + (kk) + ca + 4);        \
    b0 = *(const float4*)(Bw + rowB + (kk) + ca);           \
    b1 = *(const float4*)(Bw + rowB + (kk) + ca + 4);       \
  } while (0)

#define WRITET(buf)                                                   \
  do {                                                                \
    As[buf][ca + 0][ra] = a0.x; As[buf][ca + 1][ra] = a0.y;           \
    As[buf][ca + 2][ra] = a0.z; As[buf][ca + 3][ra] = a0.w;           \
    As[buf][ca + 4][ra] = a1.x; As[buf][ca + 5][ra] = a1.y;           \
    As[buf][ca + 6][ra] = a1.z; As[buf][ca + 7][ra] = a1.w;           \
    Bs[buf][ca + 0][ra] = b0.x; Bs[buf][ca + 1][ra] = b0.y;           \
    Bs[buf][ca + 2][ra] = b0.z; Bs[buf][ca + 3][ra] = b0.w;           \
    Bs[buf][ca + 4][ra] = b1.x; Bs[buf][ca + 5][ra] = b1.y;           \
    Bs[buf][ca + 6][ra] = b1.z; Bs[buf][ca + 7][ra] = b1.w;           \
  } while (0)

#define COMPUTET(buf)                                                 \
  do {                                                                \
    _Pragma("unroll")                                                 \
    for (int k = 0; k < 16; ++k) {                                    \
      float ar[8], br[8];                                             \
      _Pragma("unroll")                                               \
      for (int i = 0; i < 8; ++i) ar[i] = As[buf][k][ty * 8 + i];     \
      _Pragma("unroll")                                               \
      for (int j = 0; j < 8; ++j) br[j] = Bs[buf][k][tx * 8 + j];     \
      _Pragma("unroll")                                               \
      for (int i = 0; i < 8; ++i)                                     \
        _Pragma("unroll")                                             \
        for (int j = 0; j < 8; ++j)                                   \
          acc[i][j] = __builtin_fmaf(ar[i], br[j], acc[i][j]);        \
    }                                                                 \
  } while (0)

  // prologue: stage tile 0 into buf 0
  LOADT(0);
  WRITET(0);
  __syncthreads();  // tile 0 ready
  // main loop: ONE barrier per tile (dbuf, r24-proven structure).
  int t = 1;
  for (int kk = 16; kk < PQ; kk += 16, ++t) {
    LOADT(kk);
    COMPUTET((t - 1) & 1);
    WRITET(t & 1);
    __syncthreads();  // tile t ready; all waves done reading buf (t-1)&1
  }
  COMPUTET((t - 1) & 1);  // last tile

#undef LOADT
#undef WRITET
#undef COMPUTET

  float* Cb = ZP + p * pstride + (size_t)(bm * 128 + ty * 8) * N + bn * 128 + tx * 8;
#pragma unroll
  for (int i = 0; i < 8; ++i)
#pragma unroll
    for (int j = 0; j < 8; ++j)
      Cb[(size_t)i * N + j] = acc[i][j];
}

// ---------- FLOAT32 LIF over TC steps + in-order panel combine, fenced ----------
// z = (((0 + P0) + P1) + ...) — bitwise-identical to round 16's creg loop.
template <int NP>
__global__ void lif_chunk(const float* __restrict__ ZP, size_t pstride,
                          const float* __restrict__ bias,
                          float* __restrict__ stC, float* __restrict__ stV,
                          float* __restrict__ stU, float* __restrict__ Sout,
                          float* __restrict__ accB, float* __restrict__ Out,
                          int ncol, int first, int last) {
  int gid = blockIdx.x * 256 + threadIdx.x;  // b*ncol + n
  int n = gid & (ncol - 1);
  float bn = bias[n];
  float c, v, u, s, acc;
  if (first) {
    c = 0.f; v = 0.f; u = 0.f; s = 0.f; acc = 0.f;
  } else {
    c = stC[gid]; v = stV[gid]; u = stU[gid];
    s = (v > 0.5f) ? 1.0f : 0.0f;              // bitwise-identical recompute
    acc = accB ? accB[gid] : 0.f;
  }
  size_t strideT = (size_t)B_ * (size_t)ncol;
#pragma unroll
  for (int tt = 0; tt < TC; ++tt) {
    float z = 0.f;
#pragma unroll
    for (int p = 0; p < NP; ++p)
      z = fencef(z + ZP[(size_t)p * pstride + (size_t)tt * strideT + gid]);
    float t1 = fencef(c * 0.5f);
    float t2 = fencef(t1 + z);
    c = fencef(t2 + bn);                       // ((c*0.5)+z)+b — np order
    float w1 = fencef(1.0f - s);
    float w2 = fencef(v * w1);
    float w3 = fencef(0.021f * s);
    float vv = fencef(w2 + w3);                // post-reset v'
    float w4 = fencef(s * 0.132f);
    float uu = fencef(u + w4);                 // post-reset u'
    float q1 = fencef(vv * vv);
    float q2 = fencef(q1 - vv);
    float q3 = fencef(q2 - uu);
    float dv = fencef(q3 + c);
    float r1 = fencef(-0.172f * vv);
    float r2 = fencef(0.529f * uu);
    float du = fencef(r1 + r2);
    v = fencef(vv + dv);
    u = fencef(uu + du);
    s = (v > 0.5f) ? 1.0f : 0.0f;
    if (Sout) Sout[(size_t)tt * strideT + gid] = s;
    acc = fencef(acc + s);                     // exact small integer
  }
  stC[gid] = c; stV[gid] = v; stU[gid] = u;
  if (accB) accB[gid] = acc;
  if (Out && last) Out[gid] = acc * 0.0625f;   // acc/16 exact
}

extern "C" void kernel_launch(void* const* d_in, const int* in_sizes, int n_in,
                              void* d_out, int out_size, void* d_ws, size_t ws_size,
                              hipStream_t stream) {
  const float* X  = (const float*)d_in[0];
  const float* W0 = (const float*)d_in[1];
  const float* b0 = (const float*)d_in[2];
  const float* W1 = (const float*)d_in[3];
  const float* b1 = (const float*)d_in[4];
  const float* W2 = (const float*)d_in[5];
  const float* b2 = (const float*)d_in[6];
  float* Out = (float*)d_out;
  char* ws = (char*)d_ws;
  constexpr size_t MB = 1024ull * 1024ull;
  // workspace layout — peak 160 MB (proven in-bounds in round 23)
  float* Xt   = (float*)(ws);               // [4096][2048] f32 = 32 MB
  float* ZP   = (float*)(ws + 32 * MB);     // 4 panels x [4096][1024] f32 = 64 MB
  float* S0c  = (float*)(ws + 96 * MB);     // [4096][1024] f32 = 16 MB
  float* S1c  = (float*)(ws + 112 * MB);    // [4096][1024] f32 = 16 MB
  float* st0c = (float*)(ws + 128 * MB);    // [1024*1024] f32 = 4 MB each
  float* st0v = (float*)(ws + 132 * MB);
  float* st0u = (float*)(ws + 136 * MB);
  float* st1c = (float*)(ws + 140 * MB);
  float* st1v = (float*)(ws + 144 * MB);
  float* st1u = (float*)(ws + 148 * MB);
  float* st2c = (float*)(ws + 152 * MB);    // [1024*512] f32 = 2 MB each
  float* st2v = (float*)(ws + 154 * MB);
  float* st2u = (float*)(ws + 156 * MB);
  float* accB = (float*)(ws + 158 * MB);    // [1024*512] f32 = 2 MB

  const size_t psH = (size_t)(TC * B_) * H0_;  // panel stride, N=1024 layers
  const size_t psO = (size_t)(TC * B_) * OUT_; // panel stride, N=512 layer

  for (int ci = 0; ci < NCHUNK; ++ci) {
    int first = (ci == 0) ? 1 : 0;
    int last = (ci == NCHUNK - 1) ? 1 : 0;
    transpose_x4<<<(B_ * IN_) / 256, 256, 0, stream>>>(X, Xt, ci * TC);
    // layer 0: K=2048 -> 4 panels; grid = 4 * 32 * 8 = 1024 blocks (4/CU)
    gemm_panel<<<4 * (TC * B_ / 128) * (H0_ / 128), 256, 0, stream>>>(
        Xt, W0, ZP, psH, H0_ / 128, IN_, H0_);
    lif_chunk<4><<<(B_ * H0_) / 256, 256, 0, stream>>>(
        ZP, psH, b0, st0c, st0v, st0u, S0c, nullptr, nullptr, H0_, first, 0);
    // layer 1: K=1024 -> 2 panels; grid = 2 * 32 * 8 = 512 blocks
    gemm_panel<<<2 * (TC * B_ / 128) * (H1_ / 128), 256, 0, stream>>>(
        S0c, W1, ZP, psH, H1_ / 128, H0_, H1_);
    lif_chunk<2><<<(B_ * H1_) / 256, 256, 0, stream>>>(
        ZP, psH, b1, st1c, st1v, st1u, S1c, nullptr, nullptr, H1_, first, 0);
    // layer 2: K=1024 -> 2 panels; grid = 2 * 32 * 4 = 256 blocks
    gemm_panel<<<2 * (TC * B_ / 128) * (OUT_ / 128), 256, 0, stream>>>(
        S1c, W2, ZP, psO, OUT_ / 128, H1_, OUT_);
    lif_chunk<2><<<(B_ * OUT_) / 256, 256, 0, stream>>>(
        ZP, psO, b2, st2c, st2v, st2u, nullptr, accB, Out, OUT_, first, last);
  }
}

// Round 26
// 1772.417 us; speedup vs baseline: 1.0784x; 1.0784x over previous
//
#include <hip/hip_runtime.h>
#include <stdint.h>

#pragma clang fp contract(off)

constexpr int B_ = 1024, IN_ = 2048, H0_ = 1024, H1_ = 1024, OUT_ = 512;
constexpr int TC = 4;        // timesteps per chunk
constexpr int NCHUNK = 4;    // 16 / TC
constexpr int PQ = 512;      // K-panel width (bitwise-verified in round 16)

// Arithmetic fence: forces the f32 value to materialize — kills FMA contraction
// and reassociation across this point even under -ffp-contract=fast.
static __device__ __forceinline__ float fencef(float x) {
  asm volatile("" : "+v"(x));
  return x;
}

// ---------- transpose chunk: X[b][i][t0..t0+3] -> Xt[tt*B + b][i] (f32) ----------
__global__ void transpose_x4(const float* __restrict__ X, float* __restrict__ Xt, int t0) {
  int idx = blockIdx.x * 256 + threadIdx.x;  // b*IN + i
  int b = idx >> 11, i = idx & (IN_ - 1);
  float4 v = *(const float4*)(X + (size_t)idx * 16 + t0);  // 4 consecutive t's
  Xt[(size_t)b * IN_ + i] = v.x;
  Xt[(size_t)(B_ + b) * IN_ + i] = v.y;
  Xt[(size_t)(2 * B_ + b) * IN_ + i] = v.z;
  Xt[(size_t)(3 * B_ + b) * IN_ + i] = v.w;
}

// ---------- f32 NT GEMM, ONE 512-panel per block, double-buffered LDS ----------
// Panel p of C[M][N]: acc = sum_{k=512p..512p+511} fma(A[m,k], B[n,k], acc),
// single accumulator, ascending k, f32 FMA — bitwise-identical chain to the
// round-16..24 passing kernels. Two LDS buffer sets, ONE barrier per K-tile
// (r24: best measured config — 1772 us total; r25's lower-LDS-ratio shape
// regressed on occupancy+conflicts, confirming this as the empirical optimum).
// BM=128, BN=64, BK=32; 256 threads; 8x4 micro-tile; 51.2 KB LDS.
__global__ __launch_bounds__(256) void gemm_panel(
    const float* __restrict__ A, const float* __restrict__ Bw,
    float* __restrict__ ZP, size_t pstride, int Ntiles, int K, int N) {
  __shared__ float As[2][32][132];  // k-major, padded
  __shared__ float Bs[2][32][68];

  // bijective XCD swizzle (all grids here are multiples of 8)
  int bid = blockIdx.x, cpx = gridDim.x >> 3;
  int wg = (bid & 7) * cpx + (bid >> 3);
  int tpp = (gridDim.x / ((K + PQ - 1) / PQ));     // tiles per panel = Mt*Nt
  int p = wg / tpp, r = wg - p * tpp;
  int bm = r / Ntiles, bn = r - bm * Ntiles;

  int tid = threadIdx.x;
  int ra = tid >> 1, ca = (tid & 1) * 16;  // A staging: row 0..127, 16-col half
  int rb = tid >> 2, cb = (tid & 3) * 8;   // B staging: row 0..63, 8-col quarter
  int tx = tid & 15, ty = tid >> 4;        // micro-tile: cols tx*4.., rows ty*8..

  float acc[8][4] = {};   // THE panel chain accumulators (init 0, ascending k)
  const size_t rowA = (size_t)(bm * 128 + ra) * K + p * PQ;
  const size_t rowB = (size_t)(bn * 64 + rb) * K + p * PQ;

  float4 a0, a1, a2, a3, b0, b1;  // staging registers

#define LOADT(kk)                                           \
  do {                                                      \
    a0 = *(const float4*)(A + rowA + (kk) + ca);            \
    a1 = *(const float4*)(A + rowA + (kk) + ca + 4);        \
    a2 = *(const float4*)(A + rowA + (kk) + ca + 8);        \
    a3 = *(const float4*)(A + rowA + (kk) + ca + 12);       \
    b0 = *(const float4*)(Bw + rowB + (kk) + cb);           \
    b1 = *(const float4*)(Bw + rowB + (kk) + cb + 4);       \
  } while (0)

#define WRITET(buf)                                                   \
  do {                                                                \
    As[buf][ca + 0][ra] = a0.x;  As[buf][ca + 1][ra] = a0.y;          \
    As[buf][ca + 2][ra] = a0.z;  As[buf][ca + 3][ra] = a0.w;          \
    As[buf][ca + 4][ra] = a1.x;  As[buf][ca + 5][ra] = a1.y;          \
    As[buf][ca + 6][ra] = a1.z;  As[buf][ca + 7][ra] = a1.w;          \
    As[buf][ca + 8][ra] = a2.x;  As[buf][ca + 9][ra] = a2.y;          \
    As[buf][ca + 10][ra] = a2.z; As[buf][ca + 11][ra] = a2.w;         \
    As[buf][ca + 12][ra] = a3.x; As[buf][ca + 13][ra] = a3.y;         \
    As[buf][ca + 14][ra] = a3.z; As[buf][ca + 15][ra] = a3.w;         \
    Bs[buf][cb + 0][rb] = b0.x;  Bs[buf][cb + 1][rb] = b0.y;          \
    Bs[buf][cb + 2][rb] = b0.z;  Bs[buf][cb + 3][rb] = b0.w;          \
    Bs[buf][cb + 4][rb] = b1.x;  Bs[buf][cb + 5][rb] = b1.y;          \
    Bs[buf][cb + 6][rb] = b1.z;  Bs[buf][cb + 7][rb] = b1.w;          \
  } while (0)

#define COMPUTET(buf)                                                 \
  do {                                                                \
    _Pragma("unroll")                                                 \
    for (int k = 0; k < 32; ++k) {                                    \
      float ar[8], br[4];                                             \
      _Pragma("unroll")                                               \
      for (int i = 0; i < 8; ++i) ar[i] = As[buf][k][ty * 8 + i];     \
      _Pragma("unroll")                                               \
      for (int j = 0; j < 4; ++j) br[j] = Bs[buf][k][tx * 4 + j];     \
      _Pragma("unroll")                                               \
      for (int i = 0; i < 8; ++i)                                     \
        _Pragma("unroll")                                             \
        for (int j = 0; j < 4; ++j)                                   \
          acc[i][j] = __builtin_fmaf(ar[i], br[j], acc[i][j]);        \
    }                                                                 \
  } while (0)

  // prologue: stage tile 0 into buf 0
  LOADT(0);
  WRITET(0);
  __syncthreads();  // tile 0 ready
  // main loop: ONE barrier per tile.
  int t = 1;
  for (int kk = 32; kk < PQ; kk += 32, ++t) {
    LOADT(kk);
    COMPUTET((t - 1) & 1);
    WRITET(t & 1);
    __syncthreads();  // tile t ready; all waves done reading buf (t-1)&1
  }
  COMPUTET((t - 1) & 1);  // last tile

#undef LOADT
#undef WRITET
#undef COMPUTET

  float* Cb = ZP + p * pstride + (size_t)(bm * 128 + ty * 8) * N + bn * 64 + tx * 4;
#pragma unroll
  for (int i = 0; i < 8; ++i)
#pragma unroll
    for (int j = 0; j < 4; ++j)
      Cb[(size_t)i * N + j] = acc[i][j];
}

// ---------- FLOAT32 LIF over TC steps + in-order panel combine, fenced ----------
// z = (((0 + P0) + P1) + ...) — bitwise-identical to round 16's creg loop.
template <int NP>
__global__ void lif_chunk(const float* __restrict__ ZP, size_t pstride,
                          const float* __restrict__ bias,
                          float* __restrict__ stC, float* __restrict__ stV,
                          float* __restrict__ stU, float* __restrict__ Sout,
                          float* __restrict__ accB, float* __restrict__ Out,
                          int ncol, int first, int last) {
  int gid = blockIdx.x * 256 + threadIdx.x;  // b*ncol + n
  int n = gid & (ncol - 1);
  float bn = bias[n];
  float c, v, u, s, acc;
  if (first) {
    c = 0.f; v = 0.f; u = 0.f; s = 0.f; acc = 0.f;
  } else {
    c = stC[gid]; v = stV[gid]; u = stU[gid];
    s = (v > 0.5f) ? 1.0f : 0.0f;              // bitwise-identical recompute
    acc = accB ? accB[gid] : 0.f;
  }
  size_t strideT = (size_t)B_ * (size_t)ncol;
#pragma unroll
  for (int tt = 0; tt < TC; ++tt) {
    float z = 0.f;
#pragma unroll
    for (int p = 0; p < NP; ++p)
      z = fencef(z + ZP[(size_t)p * pstride + (size_t)tt * strideT + gid]);
    float t1 = fencef(c * 0.5f);
    float t2 = fencef(t1 + z);
    c = fencef(t2 + bn);                       // ((c*0.5)+z)+b — np order
    float w1 = fencef(1.0f - s);
    float w2 = fencef(v * w1);
    float w3 = fencef(0.021f * s);
    float vv = fencef(w2 + w3);                // post-reset v'
    float w4 = fencef(s * 0.132f);
    float uu = fencef(u + w4);                 // post-reset u'
    float q1 = fencef(vv * vv);
    float q2 = fencef(q1 - vv);
    float q3 = fencef(q2 - uu);
    float dv = fencef(q3 + c);
    float r1 = fencef(-0.172f * vv);
    float r2 = fencef(0.529f * uu);
    float du = fencef(r1 + r2);
    v = fencef(vv + dv);
    u = fencef(uu + du);
    s = (v > 0.5f) ? 1.0f : 0.0f;
    if (Sout) Sout[(size_t)tt * strideT + gid] = s;
    acc = fencef(acc + s);                     // exact small integer
  }
  stC[gid] = c; stV[gid] = v; stU[gid] = u;
  if (accB) accB[gid] = acc;
  if (Out && last) Out[gid] = acc * 0.0625f;   // acc/16 exact
}

extern "C" void kernel_launch(void* const* d_in, const int* in_sizes, int n_in,
                              void* d_out, int out_size, void* d_ws, size_t ws_size,
                              hipStream_t stream) {
  const float* X  = (const float*)d_in[0];
  const float* W0 = (const float*)d_in[1];
  const float* b0 = (const float*)d_in[2];
  const float* W1 = (const float*)d_in[3];
  const float* b1 = (const float*)d_in[4];
  const float* W2 = (const float*)d_in[5];
  const float* b2 = (const float*)d_in[6];
  float* Out = (float*)d_out;
  char* ws = (char*)d_ws;
  constexpr size_t MB = 1024ull * 1024ull;
  // workspace layout — peak 160 MB (proven in-bounds in round 23)
  float* Xt   = (float*)(ws);               // [4096][2048] f32 = 32 MB
  float* ZP   = (float*)(ws + 32 * MB);     // 4 panels x [4096][1024] f32 = 64 MB
  float* S0c  = (float*)(ws + 96 * MB);     // [4096][1024] f32 = 16 MB
  float* S1c  = (float*)(ws + 112 * MB);    // [4096][1024] f32 = 16 MB
  float* st0c = (float*)(ws + 128 * MB);    // [1024*1024] f32 = 4 MB each
  float* st0v = (float*)(ws + 132 * MB);
  float* st0u = (float*)(ws + 136 * MB);
  float* st1c = (float*)(ws + 140 * MB);
  float* st1v = (float*)(ws + 144 * MB);
  float* st1u = (float*)(ws + 148 * MB);
  float* st2c = (float*)(ws + 152 * MB);    // [1024*512] f32 = 2 MB each
  float* st2v = (float*)(ws + 154 * MB);
  float* st2u = (float*)(ws + 156 * MB);
  float* accB = (float*)(ws + 158 * MB);    // [1024*512] f32 = 2 MB

  const size_t psH = (size_t)(TC * B_) * H0_;  // panel stride, N=1024 layers
  const size_t psO = (size_t)(TC * B_) * OUT_; // panel stride, N=512 layer

  for (int ci = 0; ci < NCHUNK; ++ci) {
    int first = (ci == 0) ? 1 : 0;
    int last = (ci == NCHUNK - 1) ? 1 : 0;
    transpose_x4<<<(B_ * IN_) / 256, 256, 0, stream>>>(X, Xt, ci * TC);
    // layer 0: K=2048 -> 4 panels; grid = 4 * 32 * 16 = 2048 blocks
    gemm_panel<<<4 * (TC * B_ / 128) * (H0_ / 64), 256, 0, stream>>>(
        Xt, W0, ZP, psH, H0_ / 64, IN_, H0_);
    lif_chunk<4><<<(B_ * H0_) / 256, 256, 0, stream>>>(
        ZP, psH, b0, st0c, st0v, st0u, S0c, nullptr, nullptr, H0_, first, 0);
    // layer 1: K=1024 -> 2 panels; grid = 2 * 32 * 16 = 1024 blocks
    gemm_panel<<<2 * (TC * B_ / 128) * (H1_ / 64), 256, 0, stream>>>(
        S0c, W1, ZP, psH, H1_ / 64, H0_, H1_);
    lif_chunk<2><<<(B_ * H1_) / 256, 256, 0, stream>>>(
        ZP, psH, b1, st1c, st1v, st1u, S1c, nullptr, nullptr, H1_, first, 0);
    // layer 2: K=1024 -> 2 panels; grid = 2 * 32 * 8 = 512 blocks
    gemm_panel<<<2 * (TC * B_ / 128) * (OUT_ / 64), 256, 0, stream>>>(
        S1c, W2, ZP, psO, OUT_ / 64, H1_, OUT_);
    lif_chunk<2><<<(B_ * OUT_) / 256, 256, 0, stream>>>(
        ZP, psO, b2, st2c, st2v, st2u, nullptr, accB, Out, OUT_, first, last);
  }
}